// Round 13
// baseline (141.998 us; speedup 1.0000x reference)
//
#include <hip/hip_runtime.h>

#define V_DIMC 2048
#define Q_DIMC 1024
#define BATCH  64
#define KC     36
#define MROWS  (BATCH * KC)          // 2304
#define W1LD   (2 * V_DIMC + Q_DIMC) // 5120

typedef __bf16 bf16_t;
typedef __attribute__((ext_vector_type(8))) __bf16 bf16x8;
typedef __attribute__((ext_vector_type(4))) __bf16 bf16x4;
typedef __attribute__((ext_vector_type(4))) float f32x4;
typedef __attribute__((ext_vector_type(16))) float f32x16;

__device__ __forceinline__ void gload16(const bf16_t* g, bf16_t* l) {
    __builtin_amdgcn_global_load_lds(
        (const __attribute__((address_space(1))) unsigned int*)(g),
        (__attribute__((address_space(3))) unsigned int*)(l), 16, 0, 0);
}

#define MFMAI(a, b, c)  __builtin_amdgcn_mfma_f32_16x16x32_bf16(a, b, c, 0, 0, 0)
#define MFMA32(a, b, c) __builtin_amdgcn_mfma_f32_32x32x16_bf16(a, b, c, 0, 0, 0)
#define BARX() __builtin_amdgcn_s_barrier()
#define LGKM0() asm volatile("s_waitcnt lgkmcnt(0)" ::: "memory")
#define VMC(n)  asm volatile("s_waitcnt vmcnt(" #n ")" ::: "memory")

// ---------------- fused fp32 -> bf16 conversion of all operands ----------------
__global__ __launch_bounds__(256) void conv_all(const float* __restrict__ v,
                                                const float* __restrict__ q,
                                                const float* __restrict__ W1,
                                                const float* __restrict__ W2,
                                                const float* __restrict__ W3,
                                                bf16_t* __restrict__ Wab,
                                                bf16_t* __restrict__ W2b,
                                                bf16_t* __restrict__ vb,
                                                bf16_t* __restrict__ W3b,
                                                bf16_t* __restrict__ Wcb,
                                                bf16_t* __restrict__ qb) {
    const int t = blockIdx.x * 256 + threadIdx.x;
    const float* src;
    bf16_t* dst;
    if (t < 2097152) {
        size_t idx = (size_t)t * 4;
        int row = (int)(idx >> 11), col = (int)(idx & 2047);
        src = (row < 2048) ? W1 + (size_t)row * W1LD + col
                           : W1 + (size_t)(row - 2048) * W1LD + V_DIMC + col;
        dst = Wab + idx;
    } else if (t < 3145728) {
        size_t idx = (size_t)(t - 2097152) * 4;
        src = W2 + idx; dst = W2b + idx;
    } else if (t < 4325376) {
        size_t idx = (size_t)(t - 3145728) * 4;
        src = v + idx; dst = vb + idx;
    } else if (t < 4587520) {
        size_t idx = (size_t)(t - 4325376) * 4;
        src = W3 + idx; dst = W3b + idx;
    } else if (t < 5111808) {
        size_t idx = (size_t)(t - 4587520) * 4;
        int row = (int)(idx >> 10), col = (int)(idx & 1023);
        src = W1 + (size_t)row * W1LD + 2 * V_DIMC + col;
        dst = Wcb + idx;
    } else {
        size_t idx = (size_t)(t - 5111808) * 4;
        src = q + idx; dst = qb + idx;
    }
    float4 f = *reinterpret_cast<const float4*>(src);
    bf16x4 o;
    o[0] = (bf16_t)f.x; o[1] = (bf16_t)f.y; o[2] = (bf16_t)f.z; o[3] = (bf16_t)f.w;
    *reinterpret_cast<bf16x4*>(dst) = o;
}

// ---------------- q-path GEMM: M=64, K=1024, block = 64x64 output tile -------
template <int MODE>
__global__ __launch_bounds__(512) void qgemm(const bf16_t* __restrict__ A,
                                             const bf16_t* __restrict__ B,
                                             void* __restrict__ out,
                                             const float* __restrict__ bias) {
    constexpr int K = 1024;
    constexpr int NDIM = (MODE == 0) ? Q_DIMC : V_DIMC;
    __shared__ float red[8][4096];
    const int tid = threadIdx.x;
    const int w = tid >> 6, l = tid & 63;
    const int n0 = blockIdx.x * 64;
    const int fr = l & 15, lq = l >> 4;
    const bf16_t* Ab = A + (size_t)(w * 128) + lq * 8;
    const bf16_t* Bb = B + (size_t)n0 * K + (size_t)(w * 128) + lq * 8;

    f32x4 acc[4][4] = {};
#pragma unroll
    for (int ks = 0; ks < 4; ++ks) {
        bf16x8 aF[4], bF[4];
#pragma unroll
        for (int mi = 0; mi < 4; ++mi)
            aF[mi] = *(const bf16x8*)(Ab + (size_t)(mi * 16 + fr) * K + ks * 32);
#pragma unroll
        for (int ni = 0; ni < 4; ++ni)
            bF[ni] = *(const bf16x8*)(Bb + (size_t)(ni * 16 + fr) * K + ks * 32);
#pragma unroll
        for (int mi = 0; mi < 4; ++mi)
#pragma unroll
            for (int ni = 0; ni < 4; ++ni)
                acc[mi][ni] = MFMAI(aF[mi], bF[ni], acc[mi][ni]);
    }

    const int rb = lq * 4;
#pragma unroll
    for (int mi = 0; mi < 4; ++mi)
#pragma unroll
        for (int ni = 0; ni < 4; ++ni)
#pragma unroll
            for (int j = 0; j < 4; ++j)
                red[w][(mi * 16 + rb + j) * 64 + ni * 16 + fr] = acc[mi][ni][j];
    __syncthreads();

    const int row = tid >> 3, cb = (tid & 7) * 8;
    float s[8] = {};
#pragma unroll
    for (int ww = 0; ww < 8; ++ww) {
        f32x4 v0 = *(const f32x4*)&red[ww][row * 64 + cb];
        f32x4 v1 = *(const f32x4*)&red[ww][row * 64 + cb + 4];
#pragma unroll
        for (int j = 0; j < 4; ++j) { s[j] += v0[j]; s[4 + j] += v1[j]; }
    }
    if (MODE == 0) {
        bf16x8 o;
#pragma unroll
        for (int j = 0; j < 8; ++j)
            o[j] = (bf16_t)fmaxf(s[j] + bias[n0 + cb + j], 0.f);
        *reinterpret_cast<bf16x8*>((bf16_t*)out + (size_t)row * NDIM + n0 + cb) = o;
    } else {
        float4 r0, r1;
        float* rr[2] = {&r0.x, &r1.x};
#pragma unroll
        for (int h = 0; h < 2; ++h)
#pragma unroll
            for (int j = 0; j < 4; ++j)
                rr[h][j] = s[h * 4 + j] + bias[n0 + cb + h * 4 + j];
        float* op = (float*)out + (size_t)row * NDIM + n0 + cb;
        *reinterpret_cast<float4*>(op) = r0;
        *reinterpret_cast<float4*>(op + 4) = r1;
    }
}

// ---------------- (MF*32)x256 two-phase GEMM, 32x32x16 MFMA: C = A * B^T -----
// R5/R12 structure (measured optimum 139.85 us) with ONLY the MFMA shape
// changed 16x16x32 -> 32x32x16: halves MFMA instruction count per phase
// (24->12 MF6), cutting MFMA pipe time 931->775 cyc/phase/SIMD (m06 vs m119
// ceilings). LDS side invariant: still exactly MW*2 + 4 ds_read_b128 per
// phase, same bytes, same 8-lanes-per-row-unit bank profile (conflict ctr
// must stay ~0). Staging/swizzle/vmcnt/barriers byte-identical to R12.
// Fragment maps (32x32x16 bf16): A/B lane l: row|col = l&31, k = (l>>5)*8.
// D: col = l&31, row = (reg&3) + 8*(reg>>2) + 4*(l>>5), reg in [0,16).
// MODE 0 (MF=6): K=2048, NT=32, grid 16x12=192 blocks, XCD-chunked swizzle.
// MODE 2 (MF=8): split-K=3 over z (11/11/10 tiles, kb=z*704); 216 blocks.
template <int MODE, int MF>
__global__ __launch_bounds__(512) void gemm8p(const bf16_t* __restrict__ A,
                                              const bf16_t* __restrict__ Bm,
                                              bf16_t* __restrict__ out0,
                                              bf16_t* __restrict__ out1,
                                              bf16_t* __restrict__ out2) {
    constexpr int K = 2048;
    constexpr int MH = MF / 2;     // staging passes (unchanged)
    constexpr int MW = MF / 2;     // 32-row M-frags per wave (3 or 4)
    const int z = (MODE == 2) ? (int)blockIdx.z : 0;
    const int NT = (MODE == 2) ? ((z == 2) ? 10 : 11) : 32;
    const int kb = (MODE == 2) ? z * 704 : 0;
    __shared__ bf16_t ldsA[2][MF * 2048];    // [buf][MF*32 rows][64]
    __shared__ bf16_t ldsB[2][2][8192];      // [buf][ks][256 rows][32]
    const int tid = threadIdx.x;
    const int w = tid >> 6, l = tid & 63;
    const int wm = w >> 2, wn = w & 3;

    int bx, by;
    if (MODE == 0) {
        // XCD-chunked bijective swizzle: grid 16x12, 8 chunks of 4x by 6y.
        const int flat = (int)blockIdx.y * 16 + (int)blockIdx.x;
        const int xcd = flat & 7, idx = flat >> 3;   // idx in [0,24)
        bx = (xcd & 3) * 4 + (idx & 3);
        by = (xcd >> 2) * 6 + (idx >> 2);
    } else {
        bx = (int)blockIdx.x; by = (int)blockIdx.y;
    }
    const int m0 = by * (MF * 32);
    const int n0 = bx * 256;
    const size_t sK = (size_t)K;

    // A staging: row = tid>>3 (+64 per pass), 16B-unit = (tid&7) ^ (row&7).
    const int arow = tid >> 3;
    const bf16_t* gA = A + (size_t)(m0 + arow) * sK + kb
                         + (size_t)(((tid & 7) ^ (arow & 7)) << 3);
    // B staging: row = tid>>2 (+128 pass1), unit = (tid&3) ^ ((row>>1)&3).
    const int brow = tid >> 2;
    const bf16_t* gB = Bm + (size_t)(n0 + brow) * sK + kb
                          + (size_t)(((tid & 3) ^ ((tid >> 3) & 3)) << 3);
    const int stW = w * 512;   // wave's linear 512-elem chunk within a pass

    auto STGA = [&](int T) {
#pragma unroll
        for (int p = 0; p < MH; ++p)
            gload16(gA + (size_t)(p * 64) * sK + (size_t)T * 64,
                    &ldsA[T & 1][p * 4096 + stW]);
    };
    auto STGB = [&](int ks, int T) {
        const bf16_t* g_ = gB + (size_t)T * 64 + ks * 32;
        gload16(g_, &ldsB[T & 1][ks][stW]);
        gload16(g_ + (size_t)128 * sK, &ldsB[T & 1][ks][4096 + stW]);
    };

    // ---- 32x32 fragment read offsets
    const int r31 = l & 31, h = l >> 5;
    const int ax7 = r31 & 7;           // A swizzle key (row&7)
    const int bx3 = (r31 >> 1) & 3;    // B swizzle key ((row>>1)&3)
    // A physical-unit byte offsets per k-slot (slot s -> logical unit 2s+h):
    const int aU0 = ((h)     ^ ax7) << 4;   // slot 0
    const int aU1 = ((2 + h) ^ ax7) << 4;   // slot 1
    const int aU2 = ((4 + h) ^ ax7) << 4;   // slot 2
    const int aU3 = ((6 + h) ^ ax7) << 4;   // slot 3
    // B within-half unit offsets (slot parity 0 -> h, parity 1 -> 2+h):
    const int bU0 = ((h)     ^ bx3) << 4;
    const int bU1 = ((2 + h) ^ bx3) << 4;

    f32x16 acc[MW][2] = {};

    // prologue: stage tile0 fully; leave B1(0) x2 in flight (entry invariant)
    STGA(0);
    STGB(0, 0);
    STGB(1, 0);
    VMC(2);
    BARX();

    for (int T = 0; T < NT; ++T) {
        const char* pa  = (const char*)&ldsA[T & 1][0] + wm * (MF * 2048);
        const char* pb0 = (const char*)&ldsB[T & 1][0][0];
        const char* pb1 = (const char*)&ldsB[T & 1][1][0];
        bf16x8 aF0[MW], aF1[MW], bF0[2], bF1[2];

        // ------------- phase 1: k 0..31 (slots 0,1), full wave tile --------
#pragma unroll
        for (int mi = 0; mi < MW; ++mi) {
            const char* base = pa + (mi * 32 + r31) * 128;
            aF0[mi] = *(const bf16x8*)(base + aU0);
            aF1[mi] = *(const bf16x8*)(base + aU1);
        }
#pragma unroll
        for (int nf = 0; nf < 2; ++nf) {
            const char* base = pb0 + (wn * 64 + nf * 32 + r31) * 64;
            bF0[nf] = *(const bf16x8*)(base + bU0);
            bF1[nf] = *(const bf16x8*)(base + bU1);
        }
        if (T + 1 < NT) {
            STGA(T + 1); STGB(0, T + 1);
            if constexpr (MF == 6) { VMC(5); } else { VMC(6); }  // drain B1(T)
        } else {
            VMC(0);
        }
        BARX(); LGKM0();
        __builtin_amdgcn_s_setprio(1);
#pragma unroll
        for (int mi = 0; mi < MW; ++mi)
#pragma unroll
            for (int nf = 0; nf < 2; ++nf) {
                acc[mi][nf] = MFMA32(aF0[mi], bF0[nf], acc[mi][nf]);
                acc[mi][nf] = MFMA32(aF1[mi], bF1[nf], acc[mi][nf]);
            }
        __builtin_amdgcn_s_setprio(0);
        BARX();

        // ------------- phase 2: k 32..63 (slots 2,3), full wave tile -------
#pragma unroll
        for (int mi = 0; mi < MW; ++mi) {
            const char* base = pa + (mi * 32 + r31) * 128;
            aF0[mi] = *(const bf16x8*)(base + aU2);
            aF1[mi] = *(const bf16x8*)(base + aU3);
        }
#pragma unroll
        for (int nf = 0; nf < 2; ++nf) {
            const char* base = pb1 + (wn * 64 + nf * 32 + r31) * 64;
            bF0[nf] = *(const bf16x8*)(base + bU0);
            bF1[nf] = *(const bf16x8*)(base + bU1);
        }
        if (T + 1 < NT) {
            STGB(1, T + 1);
            VMC(2);                                 // drain A(T+1)+B0(T+1)
        } else {
            VMC(0);
        }
        BARX(); LGKM0();
        __builtin_amdgcn_s_setprio(1);
#pragma unroll
        for (int mi = 0; mi < MW; ++mi)
#pragma unroll
            for (int nf = 0; nf < 2; ++nf) {
                acc[mi][nf] = MFMA32(aF0[mi], bF0[nf], acc[mi][nf]);
                acc[mi][nf] = MFMA32(aF1[mi], bF1[nf], acc[mi][nf]);
            }
        __builtin_amdgcn_s_setprio(0);
        BARX();
    }

    // ---------------- epilogue (32x32 D layout) ----------------
    bf16_t* o;
    int gn0;
    if (MODE == 0) {
        if (n0 < V_DIMC) { o = out0; gn0 = n0; }
        else             { o = out1; gn0 = n0 - V_DIMC; }
    } else {
        o = (z == 0) ? out0 : (z == 1) ? out1 : out2;
        gn0 = n0;
    }
#pragma unroll
    for (int mi = 0; mi < MW; ++mi)
#pragma unroll
        for (int nf = 0; nf < 2; ++nf) {
            const int gn = gn0 + wn * 64 + nf * 32 + r31;
            const size_t gmb = (size_t)(m0 + wm * (MF * 16) + mi * 32 + 4 * h);
#pragma unroll
            for (int g = 0; g < 4; ++g)
#pragma unroll
                for (int j = 0; j < 4; ++j)
                    o[(gmb + g * 8 + j) * V_DIMC + gn] = (bf16_t)acc[mi][nf][g * 4 + j];
        }
}

// ---------------- reduce: out = relu(p0 + p1 + p2 + b2) ----------------
__global__ __launch_bounds__(256) void reduce_out(const bf16_t* __restrict__ p0,
                                                  const bf16_t* __restrict__ p1,
                                                  const bf16_t* __restrict__ p2,
                                                  const float* __restrict__ b2,
                                                  float* __restrict__ out) {
    const size_t t = (size_t)blockIdx.x * 256 + threadIdx.x;
    const size_t idx = t * 8;
    bf16x8 a = *reinterpret_cast<const bf16x8*>(p0 + idx);
    bf16x8 b = *reinterpret_cast<const bf16x8*>(p1 + idx);
    bf16x8 c = *reinterpret_cast<const bf16x8*>(p2 + idx);
    const int col = (int)(idx & (V_DIMC - 1));
    float4 r0, r1;
    float* rr[2] = {&r0.x, &r1.x};
#pragma unroll
    for (int h = 0; h < 2; ++h)
#pragma unroll
        for (int j = 0; j < 4; ++j)
            rr[h][j] = fmaxf((float)a[h * 4 + j] + (float)b[h * 4 + j] +
                             (float)c[h * 4 + j] + b2[col + h * 4 + j], 0.f);
    *reinterpret_cast<float4*>(out + idx) = r0;
    *reinterpret_cast<float4*>(out + idx + 4) = r1;
}

// ---------------- pairwise: X[b,k,v] = sum_j relu(A[b,k,v] + Bp[b,j,v] + c[b,v]) ----------------
__global__ __launch_bounds__(256) void pair_kernel(const bf16_t* __restrict__ A,
                                                   const bf16_t* __restrict__ Bp,
                                                   const float* __restrict__ cbuf,
                                                   bf16_t* __restrict__ X) {
    const int v = blockIdx.x * 256 + threadIdx.x;
    const int b = blockIdx.y;
    const float cc = cbuf[b * V_DIMC + v];
    const bf16_t* Ab = A + (size_t)b * KC * V_DIMC + v;
    const bf16_t* Bb = Bp + (size_t)b * KC * V_DIMC + v;
    float av[KC], bv[KC];
#pragma unroll
    for (int k = 0; k < KC; ++k) {
        av[k] = (float)Ab[(size_t)k * V_DIMC] + cc;
        bv[k] = (float)Bb[(size_t)k * V_DIMC];
    }
    bf16_t* Xb = X + (size_t)b * KC * V_DIMC + v;
#pragma unroll
    for (int k = 0; k < KC; ++k) {
        float s = 0.f;
#pragma unroll
        for (int j = 0; j < KC; ++j) s += fmaxf(av[k] + bv[j], 0.f);
        Xb[(size_t)k * V_DIMC] = (bf16_t)s;
    }
}

extern "C" void kernel_launch(void* const* d_in, const int* in_sizes, int n_in,
                              void* d_out, int out_size, void* d_ws, size_t ws_size,
                              hipStream_t stream) {
    const float* v  = (const float*)d_in[0];
    const float* q  = (const float*)d_in[1];
    const float* W1 = (const float*)d_in[2];
    const float* b1 = (const float*)d_in[3];
    const float* W2 = (const float*)d_in[4];
    const float* b2 = (const float*)d_in[5];
    const float* W3 = (const float*)d_in[6];
    const float* b3 = (const float*)d_in[7];
    float* out = (float*)d_out;

    char* wsb = (char*)d_ws;
    bf16_t* Wab_b = (bf16_t*)wsb;                            // 16 MiB; later Xb
    bf16_t* W2b   = (bf16_t*)(wsb + 16777216ull);            // 8 MiB
    bf16_t* vb    = (bf16_t*)(wsb + 25165824ull);            // 9 MiB; later partial2
    bf16_t* Abf   = (bf16_t*)(wsb + 34603008ull);            // 9 MiB; later partial0
    bf16_t* W3b   = (bf16_t*)(wsb + 34603008ull);            // alias (2 MiB)
    bf16_t* Wcb   = (bf16_t*)(wsb + 34603008ull + 2097152);  // alias (4 MiB)
    bf16_t* qb    = (bf16_t*)(wsb + 34603008ull + 6291456);  // alias (128 KiB)
    bf16_t* Bbf   = (bf16_t*)(wsb + 44040192ull);            // 9 MiB; later partial1
    bf16_t* qemb  = (bf16_t*)(wsb + 53477376ull);
    float*  cbuf  = (float*) (wsb + 53608448ull);
    bf16_t* Xb    = Wab_b;

    conv_all<<<dim3(20032), 256, 0, stream>>>(v, q, W1, W2, W3, Wab_b, W2b, vb, W3b, Wcb, qb);
    // q-path: q_emb = relu(q@W3^T + b3) [64x1024], cbuf = q_emb@Wc^T + b1 [64x2048]
    qgemm<0><<<dim3(Q_DIMC / 64), 512, 0, stream>>>(qb, W3b, qemb, b3);
    qgemm<1><<<dim3(V_DIMC / 64), 512, 0, stream>>>(qemb, Wcb, cbuf, b1);

    // a / bpart: M=2304, N=4096 (Wa|Wb), K=2048 — 192 blocks of 192x256
    gemm8p<0, 6><<<dim3(4096 / 256, MROWS / 192), 512, 0, stream>>>(vb, Wab_b, Abf, Bbf, nullptr);
    pair_kernel<<<dim3(V_DIMC / 256, BATCH), 256, 0, stream>>>(Abf, Bbf, cbuf, Xb);
    // final GEMM, split-K=3 over z (11/11/10 K-tiles): partials -> Abf/Bbf/vb
    gemm8p<2, 8><<<dim3(V_DIMC / 256, MROWS / 256, 3), 512, 0, stream>>>(Xb, W2b, Abf, Bbf, vb);
    reduce_out<<<dim3((MROWS * V_DIMC / 8) / 256), 256, 0, stream>>>(Abf, Bbf, vb, b2, out);
}

// Round 14
// 139.448 us; speedup vs baseline: 1.0183x; 1.0183x over previous
//
#include <hip/hip_runtime.h>

#define V_DIMC 2048
#define Q_DIMC 1024
#define BATCH  64
#define KC     36
#define MROWS  (BATCH * KC)          // 2304
#define W1LD   (2 * V_DIMC + Q_DIMC) // 5120

typedef __bf16 bf16_t;
typedef __attribute__((ext_vector_type(8))) __bf16 bf16x8;
typedef __attribute__((ext_vector_type(4))) __bf16 bf16x4;
typedef __attribute__((ext_vector_type(4))) float f32x4;

__device__ __forceinline__ void gload16(const bf16_t* g, bf16_t* l) {
    __builtin_amdgcn_global_load_lds(
        (const __attribute__((address_space(1))) unsigned int*)(g),
        (__attribute__((address_space(3))) unsigned int*)(l), 16, 0, 0);
}

#define MFMAI(a, b, c) __builtin_amdgcn_mfma_f32_16x16x32_bf16(a, b, c, 0, 0, 0)
#define BARX() __builtin_amdgcn_s_barrier()
#define LGKM0() asm volatile("s_waitcnt lgkmcnt(0)" ::: "memory")
#define VMC(n)  asm volatile("s_waitcnt vmcnt(" #n ")" ::: "memory")

// ---------------- fused fp32 -> bf16 conversion of all operands ----------------
__global__ __launch_bounds__(256) void conv_all(const float* __restrict__ v,
                                                const float* __restrict__ q,
                                                const float* __restrict__ W1,
                                                const float* __restrict__ W2,
                                                const float* __restrict__ W3,
                                                bf16_t* __restrict__ Wab,
                                                bf16_t* __restrict__ W2b,
                                                bf16_t* __restrict__ vb,
                                                bf16_t* __restrict__ W3b,
                                                bf16_t* __restrict__ Wcb,
                                                bf16_t* __restrict__ qb) {
    const int t = blockIdx.x * 256 + threadIdx.x;
    const float* src;
    bf16_t* dst;
    if (t < 2097152) {
        size_t idx = (size_t)t * 4;
        int row = (int)(idx >> 11), col = (int)(idx & 2047);
        src = (row < 2048) ? W1 + (size_t)row * W1LD + col
                           : W1 + (size_t)(row - 2048) * W1LD + V_DIMC + col;
        dst = Wab + idx;
    } else if (t < 3145728) {
        size_t idx = (size_t)(t - 2097152) * 4;
        src = W2 + idx; dst = W2b + idx;
    } else if (t < 4325376) {
        size_t idx = (size_t)(t - 3145728) * 4;
        src = v + idx; dst = vb + idx;
    } else if (t < 4587520) {
        size_t idx = (size_t)(t - 4325376) * 4;
        src = W3 + idx; dst = W3b + idx;
    } else if (t < 5111808) {
        size_t idx = (size_t)(t - 4587520) * 4;
        int row = (int)(idx >> 10), col = (int)(idx & 1023);
        src = W1 + (size_t)row * W1LD + 2 * V_DIMC + col;
        dst = Wcb + idx;
    } else {
        size_t idx = (size_t)(t - 5111808) * 4;
        src = q + idx; dst = qb + idx;
    }
    float4 f = *reinterpret_cast<const float4*>(src);
    bf16x4 o;
    o[0] = (bf16_t)f.x; o[1] = (bf16_t)f.y; o[2] = (bf16_t)f.z; o[3] = (bf16_t)f.w;
    *reinterpret_cast<bf16x4*>(dst) = o;
}

// ---------------- q-path GEMM: M=64, K=1024, block = 64x64 output tile -------
// 512 threads = 8 waves; wave w owns K-slice [w*128, w*128+128): reads A/B
// fragments DIRECTLY global->registers (no barriers in the dot loop, full ILP
// latency hiding), accumulates 4x4 frags, then cross-wave reduce via 128 KiB
// LDS + bias epilogue.
// MODE 0: out = bf16 relu(acc + bias), NDIM=1024 (q_emb).
// MODE 1: out = f32 (acc + bias), NDIM=2048 (cbuf).
template <int MODE>
__global__ __launch_bounds__(512) void qgemm(const bf16_t* __restrict__ A,
                                             const bf16_t* __restrict__ B,
                                             void* __restrict__ out,
                                             const float* __restrict__ bias) {
    constexpr int K = 1024;
    constexpr int NDIM = (MODE == 0) ? Q_DIMC : V_DIMC;
    __shared__ float red[8][4096];
    const int tid = threadIdx.x;
    const int w = tid >> 6, l = tid & 63;
    const int n0 = blockIdx.x * 64;
    const int fr = l & 15, lq = l >> 4;
    const bf16_t* Ab = A + (size_t)(w * 128) + lq * 8;
    const bf16_t* Bb = B + (size_t)n0 * K + (size_t)(w * 128) + lq * 8;

    f32x4 acc[4][4] = {};
#pragma unroll
    for (int ks = 0; ks < 4; ++ks) {
        bf16x8 aF[4], bF[4];
#pragma unroll
        for (int mi = 0; mi < 4; ++mi)
            aF[mi] = *(const bf16x8*)(Ab + (size_t)(mi * 16 + fr) * K + ks * 32);
#pragma unroll
        for (int ni = 0; ni < 4; ++ni)
            bF[ni] = *(const bf16x8*)(Bb + (size_t)(ni * 16 + fr) * K + ks * 32);
#pragma unroll
        for (int mi = 0; mi < 4; ++mi)
#pragma unroll
            for (int ni = 0; ni < 4; ++ni)
                acc[mi][ni] = MFMAI(aF[mi], bF[ni], acc[mi][ni]);
    }

    // write partials: C-frag (row = mi*16 + lq*4 + j, col = ni*16 + fr)
    const int rb = lq * 4;
#pragma unroll
    for (int mi = 0; mi < 4; ++mi)
#pragma unroll
        for (int ni = 0; ni < 4; ++ni)
#pragma unroll
            for (int j = 0; j < 4; ++j)
                red[w][(mi * 16 + rb + j) * 64 + ni * 16 + fr] = acc[mi][ni][j];
    __syncthreads();

    // each thread: 8 consecutive outputs of row tid>>3
    const int row = tid >> 3, cb = (tid & 7) * 8;
    float s[8] = {};
#pragma unroll
    for (int ww = 0; ww < 8; ++ww) {
        f32x4 v0 = *(const f32x4*)&red[ww][row * 64 + cb];
        f32x4 v1 = *(const f32x4*)&red[ww][row * 64 + cb + 4];
#pragma unroll
        for (int j = 0; j < 4; ++j) { s[j] += v0[j]; s[4 + j] += v1[j]; }
    }
    if (MODE == 0) {
        bf16x8 o;
#pragma unroll
        for (int j = 0; j < 8; ++j)
            o[j] = (bf16_t)fmaxf(s[j] + bias[n0 + cb + j], 0.f);
        *reinterpret_cast<bf16x8*>((bf16_t*)out + (size_t)row * NDIM + n0 + cb) = o;
    } else {
        float4 r0, r1;
        float* rr[2] = {&r0.x, &r1.x};
#pragma unroll
        for (int h = 0; h < 2; ++h)
#pragma unroll
            for (int j = 0; j < 4; ++j)
                rr[h][j] = s[h * 4 + j] + bias[n0 + cb + h * 4 + j];
        float* op = (float*)out + (size_t)row * NDIM + n0 + cb;
        *reinterpret_cast<float4*>(op) = r0;
        *reinterpret_cast<float4*>(op + 4) = r1;
    }
}

// ---------------- (MF*32)x256 two-phase MFMA GEMM: C = A * B^T ---------------
// THE MEASURED OPTIMUM (R5 = R12: gemm1 55.7 us, total 139.85, reproduced
// twice within 0.01 us). All nine perturbations regressed or raced:
//   R6  single end-of-tile VMC(0)            +3 us   (counted waits matter)
//   R7  B direct global->reg                 FAILED  (vmcnt miscount race)
//   R8  B direct, fixed counts               +25 us  (uncoalesced 64-row gather)
//   R9  one-barrier tile                     +9 us   (lockstep pacing is load-bearing)
//   R10 stage-issue hoist above reads        +13 us  (read burst must go first)
//   R11 128^2 2-blocks/CU                    +15 us  (occupancy didn't rise; AI halved)
//   R13 32x32x16 MFMA                        +2 us   (4-way LDS conflict: 32 rows
//        over 8 swizzle classes at 128B=bank-period stride; ctr 0 -> 3.9M)
// 512 threads = 8 waves (2M x 4N), wave tile (MF*16)x64, BK=64, double-buffered
// LDS. TWO phases per K-tile (one per k-slot): each phase = MF*4 MFMA against
// MF+4 ds_read_b128. Swizzles conflict-free (measured 0).
// ALL stages target the other buffer (tile T+1 only): race-free because
// tile T-1's readers drained at its ph2 LGKM0+barrier, before any T+1 stage.
// Counted vmcnt per tile:
//   ph1: read ks0 (A MF + B0 4); STGA(T+1)[MH] + STGB0(T+1)[2]; VMC(MH+2)
//        -> drains B1(T) staged last tile; leaves MH+2 in flight.
//   ph2: read ks1;               STGB1(T+1)[2];                VMC(2)
//        -> drains A(T+1)+B0(T+1); leaves B1(T+1). 1 full MFMA phase of
//        cover for every wait. Tail: VMC(0).
// MODE 0 (MF=6): K=2048, NT=32, grid 16x12=192 blocks, XCD-chunked swizzle:
//   each XCD's 24 blocks form a 4x by 6y chunk (FETCH 34.9 MB measured).
// MODE 2 (MF=8): split-K=3 over blockIdx.z (11/11/10 tiles, kb=z*704) -> bf16
//   partials out0/out1/out2; 216 blocks.
template <int MODE, int MF>
__global__ __launch_bounds__(512) void gemm8p(const bf16_t* __restrict__ A,
                                              const bf16_t* __restrict__ Bm,
                                              bf16_t* __restrict__ out0,
                                              bf16_t* __restrict__ out1,
                                              bf16_t* __restrict__ out2) {
    constexpr int K = 2048;
    constexpr int MH = MF / 2;
    const int z = (MODE == 2) ? (int)blockIdx.z : 0;
    const int NT = (MODE == 2) ? ((z == 2) ? 10 : 11) : 32;
    const int kb = (MODE == 2) ? z * 704 : 0;
    __shared__ bf16_t ldsA[2][MF * 2048];    // [buf][MF*32 rows][64]
    __shared__ bf16_t ldsB[2][2][8192];      // [buf][ks][256 rows][32]
    const int tid = threadIdx.x;
    const int w = tid >> 6, l = tid & 63;
    const int wm = w >> 2, wn = w & 3;

    int bx, by;
    if (MODE == 0) {
        // XCD-chunked bijective swizzle: grid 16x12, 8 chunks of 4x by 6y.
        const int flat = (int)blockIdx.y * 16 + (int)blockIdx.x;
        const int xcd = flat & 7, idx = flat >> 3;   // idx in [0,24)
        bx = (xcd & 3) * 4 + (idx & 3);
        by = (xcd >> 2) * 6 + (idx >> 2);
    } else {
        bx = (int)blockIdx.x; by = (int)blockIdx.y;
    }
    const int m0 = by * (MF * 32);
    const int n0 = bx * 256;
    const size_t sK = (size_t)K;

    // A staging: row = tid>>3 (+64 per pass), 16B-unit = (tid&7) ^ (row&7).
    const int arow = tid >> 3;
    const bf16_t* gA = A + (size_t)(m0 + arow) * sK + kb
                         + (size_t)(((tid & 7) ^ (arow & 7)) << 3);
    // B staging: row = tid>>2 (+128 pass1), unit = (tid&3) ^ ((row>>1)&3).
    const int brow = tid >> 2;
    const bf16_t* gB = Bm + (size_t)(n0 + brow) * sK + kb
                          + (size_t)(((tid & 3) ^ ((tid >> 3) & 3)) << 3);
    const int stW = w * 512;   // wave's linear 512-elem chunk within a pass

    auto STGA = [&](int T) {
#pragma unroll
        for (int p = 0; p < MH; ++p)
            gload16(gA + (size_t)(p * 64) * sK + (size_t)T * 64,
                    &ldsA[T & 1][p * 4096 + stW]);
    };
    auto STGB = [&](int ks, int T) {
        const bf16_t* g_ = gB + (size_t)T * 64 + ks * 32;
        gload16(g_, &ldsB[T & 1][ks][stW]);
        gload16(g_ + (size_t)128 * sK, &ldsB[T & 1][ks][4096 + stW]);
    };

    // ---- fragment read offsets
    const int fr = l & 15, lq = l >> 4;
    const int sw0 = (lq ^ (fr & 7)) << 4;          // A k-slot0: unit lq
    const int sw1 = ((4 | lq) ^ (fr & 7)) << 4;    // A k-slot1: unit 4+lq
    const int bsw = (lq ^ ((fr >> 1) & 3)) << 4;   // B: unit within 32-col half
    const int aro = fr * 128;                      // byte offset within A rows
    const int bro = (wn * 64 + fr) * 64 + bsw;     // + ni*1024 (bytes)

    f32x4 acc[MF][4] = {};

    // prologue: stage tile0 fully; leave B1(0) x2 in flight (entry invariant)
    STGA(0);
    STGB(0, 0);
    STGB(1, 0);
    VMC(2);
    BARX();

    for (int T = 0; T < NT; ++T) {
        const char* pa  = (const char*)&ldsA[T & 1][0] + wm * (MF * 2048);
        const char* pb0 = (const char*)&ldsB[T & 1][0][0];
        const char* pb1 = (const char*)&ldsB[T & 1][1][0];
        bf16x8 aF[MF], bF[4];

        // ---------------- phase 1: k-slot 0, full wave tile ----------------
#pragma unroll
        for (int mi = 0; mi < MF; ++mi)
            aF[mi] = *(const bf16x8*)(pa + mi * 2048 + aro + sw0);
#pragma unroll
        for (int ni = 0; ni < 4; ++ni)
            bF[ni] = *(const bf16x8*)(pb0 + bro + ni * 1024);
        if (T + 1 < NT) {
            STGA(T + 1); STGB(0, T + 1);
            if constexpr (MF == 6) { VMC(5); } else { VMC(6); }  // drain B1(T)
        } else {
            VMC(0);
        }
        BARX(); LGKM0();
        __builtin_amdgcn_s_setprio(1);
#pragma unroll
        for (int mi = 0; mi < MF; ++mi)
#pragma unroll
            for (int ni = 0; ni < 4; ++ni)
                acc[mi][ni] = MFMAI(aF[mi], bF[ni], acc[mi][ni]);
        __builtin_amdgcn_s_setprio(0);
        BARX();

        // ---------------- phase 2: k-slot 1, full wave tile ----------------
#pragma unroll
        for (int mi = 0; mi < MF; ++mi)
            aF[mi] = *(const bf16x8*)(pa + mi * 2048 + aro + sw1);
#pragma unroll
        for (int ni = 0; ni < 4; ++ni)
            bF[ni] = *(const bf16x8*)(pb1 + bro + ni * 1024);
        if (T + 1 < NT) {
            STGB(1, T + 1);
            VMC(2);                                 // drain A(T+1)+B0(T+1)
        } else {
            VMC(0);
        }
        BARX(); LGKM0();
        __builtin_amdgcn_s_setprio(1);
#pragma unroll
        for (int mi = 0; mi < MF; ++mi)
#pragma unroll
            for (int ni = 0; ni < 4; ++ni)
                acc[mi][ni] = MFMAI(aF[mi], bF[ni], acc[mi][ni]);
        __builtin_amdgcn_s_setprio(0);
        BARX();
    }

    // ---------------- epilogue ----------------
    bf16_t* o;
    int gn0;
    if (MODE == 0) {
        if (n0 < V_DIMC) { o = out0; gn0 = n0; }
        else             { o = out1; gn0 = n0 - V_DIMC; }
    } else {
        o = (z == 0) ? out0 : (z == 1) ? out1 : out2;
        gn0 = n0;
    }
    const int rb = lq * 4;
#pragma unroll
    for (int mi = 0; mi < MF; ++mi)
#pragma unroll
        for (int ni = 0; ni < 4; ++ni) {
            const size_t gm = (size_t)(m0 + wm * (MF * 16) + mi * 16 + rb);
            const int gn = gn0 + wn * 64 + ni * 16 + fr;
#pragma unroll
            for (int r = 0; r < 4; ++r)
                o[(gm + r) * V_DIMC + gn] = (bf16_t)acc[mi][ni][r];
        }
}

// ---------------- reduce: out = relu(p0 + p1 + p2 + b2) ----------------
__global__ __launch_bounds__(256) void reduce_out(const bf16_t* __restrict__ p0,
                                                  const bf16_t* __restrict__ p1,
                                                  const bf16_t* __restrict__ p2,
                                                  const float* __restrict__ b2,
                                                  float* __restrict__ out) {
    const size_t t = (size_t)blockIdx.x * 256 + threadIdx.x;
    const size_t idx = t * 8;
    bf16x8 a = *reinterpret_cast<const bf16x8*>(p0 + idx);
    bf16x8 b = *reinterpret_cast<const bf16x8*>(p1 + idx);
    bf16x8 c = *reinterpret_cast<const bf16x8*>(p2 + idx);
    const int col = (int)(idx & (V_DIMC - 1));
    float4 r0, r1;
    float* rr[2] = {&r0.x, &r1.x};
#pragma unroll
    for (int h = 0; h < 2; ++h)
#pragma unroll
        for (int j = 0; j < 4; ++j)
            rr[h][j] = fmaxf((float)a[h * 4 + j] + (float)b[h * 4 + j] +
                             (float)c[h * 4 + j] + b2[col + h * 4 + j], 0.f);
    *reinterpret_cast<float4*>(out + idx) = r0;
    *reinterpret_cast<float4*>(out + idx + 4) = r1;
}

// ---------------- pairwise: X[b,k,v] = sum_j relu(A[b,k,v] + Bp[b,j,v] + c[b,v]) ----------------
__global__ __launch_bounds__(256) void pair_kernel(const bf16_t* __restrict__ A,
                                                   const bf16_t* __restrict__ Bp,
                                                   const float* __restrict__ cbuf,
                                                   bf16_t* __restrict__ X) {
    const int v = blockIdx.x * 256 + threadIdx.x;
    const int b = blockIdx.y;
    const float cc = cbuf[b * V_DIMC + v];
    const bf16_t* Ab = A + (size_t)b * KC * V_DIMC + v;
    const bf16_t* Bb = Bp + (size_t)b * KC * V_DIMC + v;
    float av[KC], bv[KC];
#pragma unroll
    for (int k = 0; k < KC; ++k) {
        av[k] = (float)Ab[(size_t)k * V_DIMC] + cc;
        bv[k] = (float)Bb[(size_t)k * V_DIMC];
    }
    bf16_t* Xb = X + (size_t)b * KC * V_DIMC + v;
#pragma unroll
    for (int k = 0; k < KC; ++k) {
        float s = 0.f;
#pragma unroll
        for (int j = 0; j < KC; ++j) s += fmaxf(av[k] + bv[j], 0.f);
        Xb[(size_t)k * V_DIMC] = (bf16_t)s;
    }
}

extern "C" void kernel_launch(void* const* d_in, const int* in_sizes, int n_in,
                              void* d_out, int out_size, void* d_ws, size_t ws_size,
                              hipStream_t stream) {
    const float* v  = (const float*)d_in[0];
    const float* q  = (const float*)d_in[1];
    const float* W1 = (const float*)d_in[2];
    const float* b1 = (const float*)d_in[3];
    const float* W2 = (const float*)d_in[4];
    const float* b2 = (const float*)d_in[5];
    const float* W3 = (const float*)d_in[6];
    const float* b3 = (const float*)d_in[7];
    float* out = (float*)d_out;

    char* wsb = (char*)d_ws;
    bf16_t* Wab_b = (bf16_t*)wsb;                            // 16 MiB; later Xb
    bf16_t* W2b   = (bf16_t*)(wsb + 16777216ull);            // 8 MiB
    bf16_t* vb    = (bf16_t*)(wsb + 25165824ull);            // 9 MiB; later partial2
    bf16_t* Abf   = (bf16_t*)(wsb + 34603008ull);            // 9 MiB; later partial0
    bf16_t* W3b   = (bf16_t*)(wsb + 34603008ull);            // alias (2 MiB)
    bf16_t* Wcb   = (bf16_t*)(wsb + 34603008ull + 2097152);  // alias (4 MiB)
    bf16_t* qb    = (bf16_t*)(wsb + 34603008ull + 6291456);  // alias (128 KiB)
    bf16_t* Bbf   = (bf16_t*)(wsb + 44040192ull);            // 9 MiB; later partial1
    bf16_t* qemb  = (bf16_t*)(wsb + 53477376ull);
    float*  cbuf  = (float*) (wsb + 53608448ull);
    bf16_t* Xb    = Wab_b;

    conv_all<<<dim3(20032), 256, 0, stream>>>(v, q, W1, W2, W3, Wab_b, W2b, vb, W3b, Wcb, qb);
    // q-path: q_emb = relu(q@W3^T + b3) [64x1024], cbuf = q_emb@Wc^T + b1 [64x2048]
    qgemm<0><<<dim3(Q_DIMC / 64), 512, 0, stream>>>(qb, W3b, qemb, b3);
    qgemm<1><<<dim3(V_DIMC / 64), 512, 0, stream>>>(qemb, Wcb, cbuf, b1);

    // a / bpart: M=2304, N=4096 (Wa|Wb), K=2048 — 192 blocks of 192x256
    gemm8p<0, 6><<<dim3(4096 / 256, MROWS / 192), 512, 0, stream>>>(vb, Wab_b, Abf, Bbf, nullptr);
    pair_kernel<<<dim3(V_DIMC / 256, BATCH), 256, 0, stream>>>(Abf, Bbf, cbuf, Xb);
    // final GEMM, split-K=3 over z (11/11/10 K-tiles): partials -> Abf/Bbf/vb
    gemm8p<2, 8><<<dim3(V_DIMC / 256, MROWS / 256, 3), 512, 0, stream>>>(Xb, W2b, Abf, Bbf, vb);
    reduce_out<<<dim3((MROWS * V_DIMC / 8) / 256), 256, 0, stream>>>(Abf, Bbf, vb, b2, out);
}